// Round 2
// baseline (242.800 us; speedup 1.0000x reference)
//
#include <hip/hip_runtime.h>

typedef float floatx4 __attribute__((ext_vector_type(4)));
typedef unsigned int uintx4 __attribute__((ext_vector_type(4)));
typedef unsigned short ushortx4 __attribute__((ext_vector_type(4)));
typedef __bf16 bf16x8 __attribute__((ext_vector_type(8)));

#define B_ 64
#define C_ 2048
#define S_ 256
#define P_ 200
#define PM_ 256   // P padded to 256 for MFMA tiling
#define ST_ 64    // s-tile per block
#define BK_ 64
#define NKT_ 32   // C_/BK_

__device__ __forceinline__ unsigned short f2bf(float f) {
  unsigned int u = __float_as_uint(f);
  u += 0x7FFFu + ((u >> 16) & 1u);   // round-to-nearest-even
  return (unsigned short)(u >> 16);
}

// ---------------- kernel 1: prototype fp32 -> padded bf16 panel + p_sq ----------------
__global__ void __launch_bounds__(256) prep_kernel(const float* __restrict__ proto,
                                                   unsigned short* __restrict__ wsp,
                                                   float* __restrict__ wpsq) {
  const int r = blockIdx.x;   // padded proto row 0..255
  const int t = threadIdx.x;
  float s = 0.f;
#pragma unroll
  for (int rep = 0; rep < 2; ++rep) {
    const int c = rep * 1024 + t * 4;
    floatx4 v = {0.f, 0.f, 0.f, 0.f};
    if (r < P_) v = *reinterpret_cast<const floatx4*>(&proto[r * C_ + c]);
    ushortx4 h;
#pragma unroll
    for (int i = 0; i < 4; ++i) { s += v[i] * v[i]; h[i] = f2bf(v[i]); }
    *reinterpret_cast<ushortx4*>(&wsp[r * C_ + c]) = h;
  }
#pragma unroll
  for (int o = 32; o > 0; o >>= 1) s += __shfl_down(s, o);
  __shared__ float red[4];
  if ((t & 63) == 0) red[t >> 6] = s;
  __syncthreads();
  if (t == 0) wpsq[r] = red[0] + red[1] + red[2] + red[3];
}

// ---------------- kernel 2: main MFMA kernel ----------------
// grid = 64 b * 4 s-tiles = 256 blocks, 512 threads (8 waves in 4(M) x 2(N) grid)
// block tile: 256(M=p) x 64(N=s), K = 2048 in steps of 64, double-buffered LDS.
// LDS subtile layout for both operands: idx(row,k) = (row>>4)*1024 + (k>>3)*128 + (row&15)*8 + (k&7)
// -> fragment ds_read_b128 is a contiguous 1KB per wave (conflict-free), and the
//    k-permutation is identical for A and B fragments (exactness by bijection argument).
__global__ void __launch_bounds__(512, 2) main_kernel(const float* __restrict__ x,
    const unsigned short* __restrict__ wsp, const float* __restrict__ wpsq,
    float* __restrict__ out_dist, float* __restrict__ out_act,
    float* __restrict__ wpmax) {
  __shared__ unsigned short As[2][16384];  // 256 x 64 bf16, subtiled
  __shared__ unsigned short Bs[2][4096];   // 64 x 64 bf16, subtiled (rows = s, k = c)
  __shared__ float xsq_lds[512];
  __shared__ float xsqf[64];
  __shared__ float psq_lds[256];
  __shared__ float pmax_lds[512];

  const int t = threadIdx.x;
  const int lane = t & 63;
  const int w = t >> 6;
  const int wm = w >> 1, wn = w & 1;
  const int lg = lane >> 4, l15 = lane & 15;
  const int b = blockIdx.x >> 2, st = blockIdx.x & 3;
  const int s0 = st << 6;

  if (t < 256) psq_lds[t] = wpsq[t];

  const int sg = t & 15;        // s-column group (4 floats)
  const int kc0 = t >> 4;       // base k-row within tile for x staging

  const float* xb = x + (size_t)b * C_ * S_ + s0 + 4 * sg;

  floatx4 acc[4][2] = {};       // [mi][ni] 16x16 fragments
  float xsq4[4] = {0.f, 0.f, 0.f, 0.f};

  // ---- prologue: stage K-tile 0 into buffer 0 ----
#pragma unroll
  for (int q = 0; q < 4; ++q) {
    const int g2 = q * 512 + t;
    const int m = g2 >> 3, kb = g2 & 7;   // coalesced: 8 lanes cover one 128B proto row chunk
    uintx4 av = *reinterpret_cast<const uintx4*>(&wsp[m * C_ + kb * 8]);
    const int dst = ((m >> 4) << 10) + (kb << 7) + ((m & 15) << 3);
    *reinterpret_cast<uintx4*>(&As[0][dst]) = av;
  }
#pragma unroll
  for (int rep = 0; rep < 2; ++rep) {
    const int kc = rep * 32 + kc0;
    floatx4 xv = *reinterpret_cast<const floatx4*>(&xb[(size_t)kc * S_]);
#pragma unroll
    for (int i = 0; i < 4; ++i) {
      xsq4[i] += xv[i] * xv[i];
      const int n = 4 * sg + i;
      Bs[0][((n >> 4) << 10) + ((kc >> 3) << 7) + ((n & 15) << 3) + (kc & 7)] = f2bf(xv[i]);
    }
  }
  __syncthreads();

  int cur = 0;
  for (int kt = 0; kt < NKT_; ++kt) {
    uintx4 av[4];
    floatx4 xv[2];
    const bool has = (kt + 1 < NKT_);
    if (has) {  // issue next-tile global loads early (T14: issue-early / write-late)
      const int ktile = (kt + 1) << 6;
#pragma unroll
      for (int q = 0; q < 4; ++q) {
        const int g2 = q * 512 + t;
        const int m = g2 >> 3, kb = g2 & 7;
        av[q] = *reinterpret_cast<const uintx4*>(&wsp[m * C_ + ktile + kb * 8]);
      }
#pragma unroll
      for (int rep = 0; rep < 2; ++rep) {
        const int kc = rep * 32 + kc0;
        xv[rep] = *reinterpret_cast<const floatx4*>(&xb[(size_t)(ktile + kc) * S_]);
      }
    }
    // ---- compute on buffer cur ----
#pragma unroll
    for (int ks = 0; ks < 2; ++ks) {
      bf16x8 afr[4], bfr[2];
#pragma unroll
      for (int mi = 0; mi < 4; ++mi) {
        const int idx = ((wm * 4 + mi) << 10) + ((ks * 4 + lg) << 7) + (l15 << 3);
        afr[mi] = *reinterpret_cast<const bf16x8*>(&As[cur][idx]);
      }
#pragma unroll
      for (int ni = 0; ni < 2; ++ni) {
        const int idx = ((wn * 2 + ni) << 10) + ((ks * 4 + lg) << 7) + (l15 << 3);
        bfr[ni] = *reinterpret_cast<const bf16x8*>(&Bs[cur][idx]);
      }
#pragma unroll
      for (int mi = 0; mi < 4; ++mi)
#pragma unroll
        for (int ni = 0; ni < 2; ++ni)
          acc[mi][ni] = __builtin_amdgcn_mfma_f32_16x16x32_bf16(afr[mi], bfr[ni], acc[mi][ni], 0, 0, 0);
    }
    // ---- write staged data into the other buffer ----
    if (has) {
      const int nb = cur ^ 1;
#pragma unroll
      for (int q = 0; q < 4; ++q) {
        const int g2 = q * 512 + t;
        const int m = g2 >> 3, kb = g2 & 7;
        const int dst = ((m >> 4) << 10) + (kb << 7) + ((m & 15) << 3);
        *reinterpret_cast<uintx4*>(&As[nb][dst]) = av[q];
      }
#pragma unroll
      for (int rep = 0; rep < 2; ++rep) {
        const int kc = rep * 32 + kc0;
#pragma unroll
        for (int i = 0; i < 4; ++i) {
          const float f = xv[rep][i];
          xsq4[i] += f * f;
          const int n = 4 * sg + i;
          Bs[nb][((n >> 4) << 10) + ((kc >> 3) << 7) + ((n & 15) << 3) + (kc & 7)] = f2bf(f);
        }
      }
    }
    __syncthreads();
    cur ^= 1;
  }

  // ---- x_sq reduction: 4 lanes sharing an s-group, then across 8 waves ----
#pragma unroll
  for (int i = 0; i < 4; ++i) {
    float v = xsq4[i];
    v += __shfl_xor(v, 16);
    v += __shfl_xor(v, 32);
    xsq4[i] = v;
  }
  if (lane < 16) {
#pragma unroll
    for (int i = 0; i < 4; ++i) xsq_lds[w * 64 + lane * 4 + i] = xsq4[i];
  }
  __syncthreads();
  if (t < 64) {
    float s = 0.f;
#pragma unroll
    for (int w2 = 0; w2 < 8; ++w2) s += xsq_lds[w2 * 64 + t];
    xsqf[t] = s;
  }
  __syncthreads();

  // ---- epilogue: distances, stores, row max ----
  // D layout (verified): col = lane&15 (s), row = (lane>>4)*4 + reg (p)
#pragma unroll
  for (int mi = 0; mi < 4; ++mi) {
#pragma unroll
    for (int r = 0; r < 4; ++r) {
      const int m = wm * 64 + mi * 16 + lg * 4 + r;
      const float ps = psq_lds[m];
      float rowmax = -3.0e38f;
#pragma unroll
      for (int ni = 0; ni < 2; ++ni) {
        const int n = wn * 32 + ni * 16 + l15;
        const float d = xsqf[n] + ps - 2.0f * acc[mi][ni][r];
        if (m < P_) {
          const int gi = ((b * P_ + m) << 8) + s0 + n;
          out_dist[gi] = d;
          out_act[gi] = -d;
        }
        rowmax = fmaxf(rowmax, -d);
      }
#pragma unroll
      for (int off = 1; off < 16; off <<= 1)
        rowmax = fmaxf(rowmax, __shfl_xor(rowmax, off));
      if (l15 == 0) pmax_lds[wn * 256 + m] = rowmax;
    }
  }
  __syncthreads();
  if (t < 256) {
    const float v = fmaxf(pmax_lds[t], pmax_lds[256 + t]);
    wpmax[(((b << 8) + t) << 2) + st] = v;
  }
}

// ---------------- kernel 3: combine the 4 s-tile partial maxima ----------------
__global__ void __launch_bounds__(256) fin_kernel(const float* __restrict__ wpmax,
                                                  float* __restrict__ out_max) {
  const int i = blockIdx.x * 256 + threadIdx.x;
  if (i >= B_ * P_) return;
  const int b = i / P_;
  const int p = i - b * P_;
  floatx4 v = *reinterpret_cast<const floatx4*>(&wpmax[((b << 8) + p) << 2]);
  out_max[i] = fmaxf(fmaxf(v[0], v[1]), fmaxf(v[2], v[3]));
}

extern "C" void kernel_launch(void* const* d_in, const int* in_sizes, int n_in,
                              void* d_out, int out_size, void* d_ws, size_t ws_size,
                              hipStream_t stream) {
  (void)in_sizes; (void)n_in; (void)out_size; (void)ws_size;
  const float* x = (const float*)d_in[0];
  const float* proto = (const float*)d_in[1];
  float* out = (float*)d_out;

  // ws layout: proto bf16 panel (1 MiB) | p_sq (1 KiB) | partial max (256 KiB)
  unsigned short* wsp = (unsigned short*)d_ws;
  float* wpsq  = (float*)((char*)d_ws + (size_t)PM_ * C_ * 2);
  float* wpmax = (float*)((char*)d_ws + (size_t)PM_ * C_ * 2 + 1024);

  float* out_max  = out;                          // (64,200)
  float* out_dist = out + B_ * P_;                // (64,200,256)
  float* out_act  = out + B_ * P_ + B_ * P_ * S_; // (64,200,16,16)

  prep_kernel<<<PM_, 256, 0, stream>>>(proto, wsp, wpsq);
  main_kernel<<<B_ * (S_ / ST_), 512, 0, stream>>>(x, wsp, wpsq, out_dist, out_act, wpmax);
  fin_kernel<<<(B_ * P_ + 255) / 256, 256, 0, stream>>>(wpmax, out_max);
}

// Round 4
// 223.145 us; speedup vs baseline: 1.0881x; 1.0881x over previous
//
#include <hip/hip_runtime.h>

typedef float floatx4 __attribute__((ext_vector_type(4)));
typedef unsigned short ushortx4 __attribute__((ext_vector_type(4)));
typedef __bf16 bf16x8 __attribute__((ext_vector_type(8)));

#define B_ 64
#define C_ 2048
#define S_ 256
#define P_ 200
#define PM_ 256
#define ST_ 32      // s-tile per block
#define NST_ 8      // S_/ST_
#define NKT_ 32     // C_/64

__device__ __forceinline__ unsigned short f2bf(float f) {
  unsigned int u = __float_as_uint(f);
  u += 0x7FFFu + ((u >> 16) & 1u);   // round-to-nearest-even
  return (unsigned short)(u >> 16);
}

// ---------------- kernel 1: prototypes -> pre-swizzled bf16 panel + p_sq ----------------
// Panel = exact LDS image per K-tile (16384 ushorts = 32KB):
//   idx(m, k_local) = (m>>4)*1024 + (k_local>>3)*128 + (m&15)*8 + (k_local&7)
// (identical to the Round-2 verified As layout; main kernel DMAs it linearly).
__global__ void __launch_bounds__(256) prep_kernel(const float* __restrict__ proto,
                                                   unsigned short* __restrict__ wsp,
                                                   float* __restrict__ wpsq) {
  const int r = blockIdx.x;   // padded proto row 0..255
  const int t = threadIdx.x;  // covers k_global = 8t..8t+7
  floatx4 v0 = {0.f,0.f,0.f,0.f}, v1 = {0.f,0.f,0.f,0.f};
  if (r < P_) {
    v0 = *reinterpret_cast<const floatx4*>(proto + (size_t)r * C_ + t * 8);
    v1 = *reinterpret_cast<const floatx4*>(proto + (size_t)r * C_ + t * 8 + 4);
  }
  float s = 0.f;
  ushortx4 h0, h1;
#pragma unroll
  for (int i = 0; i < 4; ++i) {
    s += v0[i]*v0[i] + v1[i]*v1[i];
    h0[i] = f2bf(v0[i]); h1[i] = f2bf(v1[i]);
  }
  const int u = (t >> 3) * 16384 + (r >> 4) * 1024 + (t & 7) * 128 + (r & 15) * 8;
  *reinterpret_cast<ushortx4*>(wsp + u) = h0;
  *reinterpret_cast<ushortx4*>(wsp + u + 4) = h1;

#pragma unroll
  for (int o = 32; o > 0; o >>= 1) s += __shfl_down(s, o);
  __shared__ float red[4];
  if ((t & 63) == 0) red[t >> 6] = s;
  __syncthreads();
  if (t == 0) wpsq[r] = red[0] + red[1] + red[2] + red[3];
}

// ---------------- kernel 2: main MFMA kernel ----------------
// grid 512 = 64 b x 8 s-tiles; 512 threads = 8 waves (wave grid 8M x 1N).
// tile 256p x 32s, BK=64, double-buffered. LDS 72KB -> 2 blocks/CU.
// As: DMA (global_load_lds) from pre-swizzled panel, dbuf 2x16384 ushorts.
// Bs: subtile layout idx(s,k) = (s>>4)*1024 + (k>>3)*128 + slot(s,s>>4)*8 + (k&7)
//     slot = (s&15) ^ ((s&8)>>1) ^ ((s>>4)<<1)   (bank-spread, bijective per region)
//   staged k-grouped: thread (w=koct, h=lane>>5, s=lane&31) loads 4 k's for one s,
//   writes ONE contiguous ds_write_b64. Fragment reads: plain ds_read_b128 with the
//   same slot swizzle -> A and B share identical (k&7) slot ordering => exact GEMM.
__global__ void __launch_bounds__(512, 4) main_kernel(const float* __restrict__ x,
    const unsigned short* __restrict__ wsp, const float* __restrict__ wpsq,
    float* __restrict__ out_dist, float* __restrict__ out_act,
    float* __restrict__ wpmax) {
  __shared__ unsigned short lds[36864];   // As dbuf 2x16384 | Bs dbuf 2x2048 (ushorts)

  const int t = threadIdx.x;
  const int lane = t & 63;
  const int w = t >> 6;                   // wave 0..7 = m-block AND staging k-octet
  const int lg = lane >> 4, l15 = lane & 15;
  const int b = blockIdx.x >> 3, st = blockIdx.x & 7;

  // B staging coords: thread covers k = w*8 + h_*4 + j (j=0..3), s = s_
  const int s_ = lane & 31;
  const int h_ = lane >> 5;
  const float* xb = x + (size_t)b * (C_ * S_) + (size_t)(w * 8 + h_ * 4) * S_ + st * ST_ + s_;

  const int slot_w = (s_ & 15) ^ ((s_ & 8) >> 1) ^ ((s_ >> 4) << 1);
  const int wr_base = 32768 + (s_ >> 4) * 1024 + w * 128 + slot_w * 8 + h_ * 4;
  const int slot_r0 = l15 ^ ((l15 & 8) >> 1);

  floatx4 acc[2][2] = {};                 // [mi][ni]
  float xsq_s = 0.f;

  // ---- prologue: stage tile 0 ----
#pragma unroll
  for (int q = 0; q < 4; ++q) {
    __builtin_amdgcn_global_load_lds(
      (const __attribute__((address_space(1))) unsigned int*)(wsp + (q * 512 + t) * 8),
      (__attribute__((address_space(3))) unsigned int*)
        ((__attribute__((address_space(3))) unsigned short*)lds + (q * 512 + t) * 8),
      16, 0, 0);
  }
  {
    float xj[4]; ushortx4 hv;
#pragma unroll
    for (int j = 0; j < 4; ++j) xj[j] = xb[j * S_];
#pragma unroll
    for (int j = 0; j < 4; ++j) { xsq_s += xj[j] * xj[j]; hv[j] = f2bf(xj[j]); }
    *reinterpret_cast<ushortx4*>(&lds[wr_base]) = hv;
  }
  __syncthreads();

  for (int kt = 0; kt < NKT_; ++kt) {
    const int cur = kt & 1, nb = cur ^ 1;
    float xj[4];
    if (kt < NKT_ - 1) {
      const unsigned short* gsrc = wsp + (size_t)(kt + 1) * 16384;
#pragma unroll
      for (int q = 0; q < 4; ++q) {
        __builtin_amdgcn_global_load_lds(
          (const __attribute__((address_space(1))) unsigned int*)(gsrc + (q * 512 + t) * 8),
          (__attribute__((address_space(3))) unsigned int*)
            ((__attribute__((address_space(3))) unsigned short*)lds + nb * 16384 + (q * 512 + t) * 8),
          16, 0, 0);
      }
      const float* xsrc = xb + (size_t)(kt + 1) * 64 * S_;
#pragma unroll
      for (int j = 0; j < 4; ++j) xj[j] = xsrc[j * S_];
    }
    // ---- compute on buffer cur ----
    {
      const unsigned short* As_c = lds + cur * 16384;
      const unsigned short* Bs_c = lds + 32768 + cur * 2048;
#pragma unroll
      for (int ks = 0; ks < 2; ++ks) {
        const int ko = (ks * 4 + lg) * 128;
        const bf16x8 a0 = *reinterpret_cast<const bf16x8*>(As_c + (w * 2 + 0) * 1024 + ko + l15 * 8);
        const bf16x8 a1 = *reinterpret_cast<const bf16x8*>(As_c + (w * 2 + 1) * 1024 + ko + l15 * 8);
        const bf16x8 b0 = *reinterpret_cast<const bf16x8*>(Bs_c + ko + slot_r0 * 8);
        const bf16x8 b1 = *reinterpret_cast<const bf16x8*>(Bs_c + 1024 + ko + (slot_r0 ^ 2) * 8);
        acc[0][0] = __builtin_amdgcn_mfma_f32_16x16x32_bf16(a0, b0, acc[0][0], 0, 0, 0);
        acc[0][1] = __builtin_amdgcn_mfma_f32_16x16x32_bf16(a0, b1, acc[0][1], 0, 0, 0);
        acc[1][0] = __builtin_amdgcn_mfma_f32_16x16x32_bf16(a1, b0, acc[1][0], 0, 0, 0);
        acc[1][1] = __builtin_amdgcn_mfma_f32_16x16x32_bf16(a1, b1, acc[1][1], 0, 0, 0);
      }
    }
    if (kt < NKT_ - 1) {
      ushortx4 hv;
#pragma unroll
      for (int j = 0; j < 4; ++j) { xsq_s += xj[j] * xj[j]; hv[j] = f2bf(xj[j]); }
      *reinterpret_cast<ushortx4*>(&lds[wr_base + nb * 2048]) = hv;
    }
    __syncthreads();
  }

  // ---- x_sq reduce: combine h halves in-wave, then across the 8 waves via LDS ----
  float* xpart = reinterpret_cast<float*>(&lds[32768]);   // alias dead Bs buf0
  float* xsqf  = xpart + 256;
  {
    const float v = xsq_s + __shfl_xor(xsq_s, 32);
    if (lane < 32) xpart[w * 32 + lane] = v;
  }
  __syncthreads();
  if (t < 32) {
    float s2 = 0.f;
#pragma unroll
    for (int w2 = 0; w2 < 8; ++w2) s2 += xpart[w2 * 32 + t];
    xsqf[t] = s2;
  }
  __syncthreads();

  // ---- epilogue: distances, stores, row max ----
  // D layout (verified): col = lane&15 (s), row = (lane>>4)*4 + reg (p)
  const float xn0 = xsqf[l15], xn1 = xsqf[16 + l15];
#pragma unroll
  for (int mi = 0; mi < 2; ++mi)
#pragma unroll
    for (int r = 0; r < 4; ++r) {
      const int m = w * 32 + mi * 16 + lg * 4 + r;
      const float ps = (m < P_) ? wpsq[m] : 0.f;
      const float d0 = xn0 + ps - 2.0f * acc[mi][0][r];
      const float d1 = xn1 + ps - 2.0f * acc[mi][1][r];
      if (m < P_) {
        const size_t gi = (size_t)(b * P_ + m) * S_ + st * ST_ + l15;
        out_dist[gi] = d0;       out_dist[gi + 16] = d1;
        out_act[gi]  = -d0;      out_act[gi + 16]  = -d1;
      }
      float rm = fmaxf(-d0, -d1);
#pragma unroll
      for (int off = 1; off < 16; off <<= 1) rm = fmaxf(rm, __shfl_xor(rm, off));
      if (l15 == 0 && m < P_) wpmax[(size_t)((b << 8) + m) * 8 + st] = rm;
    }
}

// ---------------- kernel 3: combine the 8 s-tile partial maxima ----------------
__global__ void __launch_bounds__(256) fin_kernel(const float* __restrict__ wpmax,
                                                  float* __restrict__ out_max) {
  const int i = blockIdx.x * 256 + threadIdx.x;
  if (i >= B_ * P_) return;
  const int b = i / P_;
  const int p = i - b * P_;
  const float* q = wpmax + (size_t)((b << 8) + p) * 8;
  const floatx4 v0 = *reinterpret_cast<const floatx4*>(q);
  const floatx4 v1 = *reinterpret_cast<const floatx4*>(q + 4);
  out_max[i] = fmaxf(fmaxf(fmaxf(v0[0], v0[1]), fmaxf(v0[2], v0[3])),
                     fmaxf(fmaxf(v1[0], v1[1]), fmaxf(v1[2], v1[3])));
}

extern "C" void kernel_launch(void* const* d_in, const int* in_sizes, int n_in,
                              void* d_out, int out_size, void* d_ws, size_t ws_size,
                              hipStream_t stream) {
  (void)in_sizes; (void)n_in; (void)out_size; (void)ws_size;
  const float* x = (const float*)d_in[0];
  const float* proto = (const float*)d_in[1];
  float* out = (float*)d_out;

  // ws: panel 1MiB | p_sq 1KiB | partial max 512KiB
  unsigned short* wsp = (unsigned short*)d_ws;
  float* wpsq  = (float*)((char*)d_ws + (size_t)NKT_ * 16384 * 2);
  float* wpmax = (float*)((char*)d_ws + (size_t)NKT_ * 16384 * 2 + 1024);

  float* out_max  = out;                          // (64,200)
  float* out_dist = out + B_ * P_;                // (64,200,256)
  float* out_act  = out + B_ * P_ + B_ * P_ * S_; // (64,200,16,16)

  prep_kernel<<<PM_, 256, 0, stream>>>(proto, wsp, wpsq);
  main_kernel<<<B_ * NST_, 512, 0, stream>>>(x, wsp, wpsq, out_dist, out_act, wpmax);
  fin_kernel<<<(B_ * P_ + 255) / 256, 256, 0, stream>>>(wpmax, out_max);
}

// Round 5
// 220.003 us; speedup vs baseline: 1.1036x; 1.0143x over previous
//
#include <hip/hip_runtime.h>

typedef float floatx4 __attribute__((ext_vector_type(4)));
typedef unsigned int uintx4 __attribute__((ext_vector_type(4)));
typedef unsigned short ushortx4 __attribute__((ext_vector_type(4)));
typedef __bf16 bf16x8 __attribute__((ext_vector_type(8)));

#define B_ 64
#define C_ 2048
#define S_ 256
#define P_ 200
#define PM_ 256
#define ST_ 32      // s-tile per block
#define NST_ 8      // S_/ST_
#define NKT_ 32     // C_/64

__device__ __forceinline__ unsigned short f2bf(float f) {
  unsigned int u = __float_as_uint(f);
  u += 0x7FFFu + ((u >> 16) & 1u);   // round-to-nearest-even
  return (unsigned short)(u >> 16);
}

// ---------------- kernel 1: prototypes -> pre-swizzled bf16 panel + p_sq ----------------
// Panel = fragment image per K-tile (16384 ushorts = 32KB):
//   idx(m, k_local) = (m>>4)*1024 + (k_local>>3)*128 + (m&15)*8 + (k_local&7)
// Main kernel loads A fragments DIRECTLY from this panel (contiguous 1KB/wave-instr).
__global__ void __launch_bounds__(256) prep_kernel(const float* __restrict__ proto,
                                                   unsigned short* __restrict__ wsp,
                                                   float* __restrict__ wpsq) {
  const int r = blockIdx.x;   // padded proto row 0..255
  const int t = threadIdx.x;  // covers k_global = 8t..8t+7
  floatx4 v0 = {0.f,0.f,0.f,0.f}, v1 = {0.f,0.f,0.f,0.f};
  if (r < P_) {
    v0 = *reinterpret_cast<const floatx4*>(proto + (size_t)r * C_ + t * 8);
    v1 = *reinterpret_cast<const floatx4*>(proto + (size_t)r * C_ + t * 8 + 4);
  }
  float s = 0.f;
  ushortx4 h0, h1;
#pragma unroll
  for (int i = 0; i < 4; ++i) {
    s += v0[i]*v0[i] + v1[i]*v1[i];
    h0[i] = f2bf(v0[i]); h1[i] = f2bf(v1[i]);
  }
  const int u = (t >> 3) * 16384 + (r >> 4) * 1024 + (t & 7) * 128 + (r & 15) * 8;
  *reinterpret_cast<ushortx4*>(wsp + u) = h0;
  *reinterpret_cast<ushortx4*>(wsp + u + 4) = h1;

#pragma unroll
  for (int o = 32; o > 0; o >>= 1) s += __shfl_down(s, o);
  __shared__ float red[4];
  if ((t & 63) == 0) red[t >> 6] = s;
  __syncthreads();
  if (t == 0) wpsq[r] = red[0] + red[1] + red[2] + red[3];
}

// ---------------- kernel 2: main MFMA kernel ----------------
// grid 512 = 64 b x 8 s-tiles; 512 threads = 8 waves (8M x 1N), 2 blocks/CU.
// A: fragments loaded global->VGPR from the pre-swizzled panel (no LDS, no DMA),
//    1 tile ahead, bytes identical to the R4 DMA+ds_read path => same numerics.
// B: LDS dbuf 2x2048 ushorts, verified swizzled layout:
//    idx(s,k) = (s>>4)*1024 + (k>>3)*128 + slot(s)*8 + (k&7),
//    slot = (s&15) ^ ((s&8)>>1) ^ ((s>>4)<<1).
// Barriers: raw s_waitcnt lgkmcnt(0) + s_barrier -> A loads stay in flight (no vmcnt drain).
__global__ void __launch_bounds__(512, 4) main_kernel(const float* __restrict__ x,
    const unsigned short* __restrict__ wsp, const float* __restrict__ wpsq,
    float* __restrict__ out_dist, float* __restrict__ out_act,
    float* __restrict__ wpmax) {
  __shared__ unsigned short lds[4096];    // B dbuf only (2 x 4KB)

  const int t = threadIdx.x;
  const int lane = t & 63;
  const int w = t >> 6;                   // wave 0..7 = m-block pair AND staging k-octet
  const int lg = lane >> 4, l15 = lane & 15;
  const int b = blockIdx.x >> 3, st = blockIdx.x & 7;

  // B staging coords: thread covers k = w*8 + h_*4 + j (j=0..3), s = s_
  const int s_ = lane & 31;
  const int h_ = lane >> 5;
  const float* xb = x + (size_t)b * (C_ * S_) + (size_t)(w * 8 + h_ * 4) * S_ + st * ST_ + s_;

  const int slot_w = (s_ & 15) ^ ((s_ & 8) >> 1) ^ ((s_ >> 4) << 1);
  const int wr_base = (s_ >> 4) * 1024 + w * 128 + slot_w * 8 + h_ * 4;
  const int slot_r0 = l15 ^ ((l15 & 8) >> 1);

  // A fragment base: panel + mb*1024 + (ks*4+lg)*128 + l15*8, mb = w*2+mi.
  // Per-thread base; frag (kt,mi,ks) at + kt*16384 + mi*1024 + ks*512.
  const unsigned short* ap = wsp + w * 2048 + lg * 128 + l15 * 8;

  floatx4 acc[2][2] = {};                 // [mi][ni]
  float xsq_s = 0.f;

#define LOADA(dst, T) do { const unsigned short* pp = ap + (size_t)(T) * 16384; \
    dst[0] = *reinterpret_cast<const uintx4*>(pp);        \
    dst[1] = *reinterpret_cast<const uintx4*>(pp + 512);  \
    dst[2] = *reinterpret_cast<const uintx4*>(pp + 1024); \
    dst[3] = *reinterpret_cast<const uintx4*>(pp + 1536); } while (0)
  // dst[mi*2+ks]

#define LOADX(xv, T) do { const float* xs = xb + (size_t)(T) * 64 * S_; \
    xv[0] = xs[0]; xv[1] = xs[S_]; xv[2] = xs[2*S_]; xv[3] = xs[3*S_]; } while (0)

#define STAGEB(buf, xv) do { ushortx4 hv;                                  \
    _Pragma("unroll") for (int j = 0; j < 4; ++j) {                        \
      xsq_s += xv[j] * xv[j]; hv[j] = f2bf(xv[j]); }                       \
    *reinterpret_cast<ushortx4*>(&lds[(buf) * 2048 + wr_base]) = hv; } while (0)

#define BARRIER() asm volatile("s_waitcnt lgkmcnt(0)\n\ts_barrier" ::: "memory")

#define COMPUTE(A, buf) do { const unsigned short* Bs_c = lds + (buf) * 2048;          \
    _Pragma("unroll") for (int ks = 0; ks < 2; ++ks) {                                  \
      const int ko = (ks * 4 + lg) * 128;                                               \
      const bf16x8 a0 = __builtin_bit_cast(bf16x8, A[ks]);                              \
      const bf16x8 a1 = __builtin_bit_cast(bf16x8, A[2 + ks]);                          \
      const bf16x8 b0 = *reinterpret_cast<const bf16x8*>(Bs_c + ko + slot_r0 * 8);      \
      const bf16x8 b1 = *reinterpret_cast<const bf16x8*>(Bs_c + 1024 + ko + (slot_r0 ^ 2) * 8); \
      acc[0][0] = __builtin_amdgcn_mfma_f32_16x16x32_bf16(a0, b0, acc[0][0], 0, 0, 0);  \
      acc[0][1] = __builtin_amdgcn_mfma_f32_16x16x32_bf16(a0, b1, acc[0][1], 0, 0, 0);  \
      acc[1][0] = __builtin_amdgcn_mfma_f32_16x16x32_bf16(a1, b0, acc[1][0], 0, 0, 0);  \
      acc[1][1] = __builtin_amdgcn_mfma_f32_16x16x32_bf16(a1, b1, acc[1][1], 0, 0, 0);  \
    } } while (0)

  // ---- prologue: tile 0 ----
  uintx4 aQ[4], aR[4];
  float xj[4];
  LOADX(xj, 0);
  LOADA(aQ, 0);
  STAGEB(0, xj);
  BARRIER();

  for (int kt = 0; kt < NKT_; kt += 2) {
    // even sub-iter: tile kt (buf0, aQ); prefetch kt+1
    float xn[4];
    LOADX(xn, kt + 1);
    LOADA(aR, kt + 1);
    COMPUTE(aQ, 0);
    STAGEB(1, xn);
    BARRIER();
    // odd sub-iter: tile kt+1 (buf1, aR); prefetch kt+2
    if (kt + 2 < NKT_) {
      float xm[4];
      LOADX(xm, kt + 2);
      LOADA(aQ, kt + 2);
      COMPUTE(aR, 1);
      STAGEB(0, xm);
      BARRIER();
    } else {
      COMPUTE(aR, 1);
    }
  }
  __syncthreads();

  // ---- x_sq reduce: combine h halves in-wave, then across the 8 waves via LDS ----
  float* xpart = reinterpret_cast<float*>(&lds[0]);   // alias dead B buffers
  float* xsqf  = xpart + 256;
  {
    const float v = xsq_s + __shfl_xor(xsq_s, 32);
    if (lane < 32) xpart[w * 32 + lane] = v;
  }
  __syncthreads();
  if (t < 32) {
    float s2 = 0.f;
#pragma unroll
    for (int w2 = 0; w2 < 8; ++w2) s2 += xpart[w2 * 32 + t];
    xsqf[t] = s2;
  }
  __syncthreads();

  // ---- epilogue: distances, stores, row max ----
  // D layout (verified): col = lane&15 (s), row = (lane>>4)*4 + reg (p)
  const float xn0 = xsqf[l15], xn1 = xsqf[16 + l15];
#pragma unroll
  for (int mi = 0; mi < 2; ++mi)
#pragma unroll
    for (int r = 0; r < 4; ++r) {
      const int m = w * 32 + mi * 16 + lg * 4 + r;
      const float ps = (m < P_) ? wpsq[m] : 0.f;
      const float d0 = xn0 + ps - 2.0f * acc[mi][0][r];
      const float d1 = xn1 + ps - 2.0f * acc[mi][1][r];
      if (m < P_) {
        const size_t gi = (size_t)(b * P_ + m) * S_ + st * ST_ + l15;
        out_dist[gi] = d0;       out_dist[gi + 16] = d1;
        out_act[gi]  = -d0;      out_act[gi + 16]  = -d1;
      }
      float rm = fmaxf(-d0, -d1);
#pragma unroll
      for (int off = 1; off < 16; off <<= 1) rm = fmaxf(rm, __shfl_xor(rm, off));
      if (l15 == 0 && m < P_) wpmax[(size_t)((b << 8) + m) * 8 + st] = rm;
    }
}

// ---------------- kernel 3: combine the 8 s-tile partial maxima ----------------
__global__ void __launch_bounds__(256) fin_kernel(const float* __restrict__ wpmax,
                                                  float* __restrict__ out_max) {
  const int i = blockIdx.x * 256 + threadIdx.x;
  if (i >= B_ * P_) return;
  const int b = i / P_;
  const int p = i - b * P_;
  const float* q = wpmax + (size_t)((b << 8) + p) * 8;
  const floatx4 v0 = *reinterpret_cast<const floatx4*>(q);
  const floatx4 v1 = *reinterpret_cast<const floatx4*>(q + 4);
  out_max[i] = fmaxf(fmaxf(fmaxf(v0[0], v0[1]), fmaxf(v0[2], v0[3])),
                     fmaxf(fmaxf(v1[0], v1[1]), fmaxf(v1[2], v1[3])));
}

extern "C" void kernel_launch(void* const* d_in, const int* in_sizes, int n_in,
                              void* d_out, int out_size, void* d_ws, size_t ws_size,
                              hipStream_t stream) {
  (void)in_sizes; (void)n_in; (void)out_size; (void)ws_size;
  const float* x = (const float*)d_in[0];
  const float* proto = (const float*)d_in[1];
  float* out = (float*)d_out;

  // ws: panel 1MiB | p_sq 1KiB | partial max 512KiB
  unsigned short* wsp = (unsigned short*)d_ws;
  float* wpsq  = (float*)((char*)d_ws + (size_t)NKT_ * 16384 * 2);
  float* wpmax = (float*)((char*)d_ws + (size_t)NKT_ * 16384 * 2 + 1024);

  float* out_max  = out;                          // (64,200)
  float* out_dist = out + B_ * P_;                // (64,200,256)
  float* out_act  = out + B_ * P_ + B_ * P_ * S_; // (64,200,16,16)

  prep_kernel<<<PM_, 256, 0, stream>>>(proto, wsp, wpsq);
  main_kernel<<<B_ * NST_, 512, 0, stream>>>(x, wsp, wpsq, out_dist, out_act, wpmax);
  fin_kernel<<<(B_ * P_ + 255) / 256, 256, 0, stream>>>(wpmax, out_max);
}